// Round 9
// baseline (72.238 us; speedup 1.0000x reference)
//
#include <hip/hip_runtime.h>
#include <hip/hip_fp16.h>

#define N_ 16
#define C_ 128
#define S_ 16384
#define K_ 64

typedef __attribute__((ext_vector_type(4))) float f32x4;
typedef __attribute__((ext_vector_type(8))) _Float16 f16x8;
typedef __attribute__((ext_vector_type(4))) _Float16 f16x4;

// xT row-swizzle: varies with staging rows s=4*s4+j AND frag rows s=16m+lr.
#define SWZ_S(s) ((((s) ^ ((s) >> 3)) & 7) << 3)

// ---------------------------------------------------------------------------
// Prep: W f32 -> f16, frag-ordered: west[((kt*4+nt)*64 + lane)*8 + e] holds
// the exact 16B B-fragment lane `lane` needs for (kt,nt) -> coalesced loads.
// ---------------------------------------------------------------------------
__global__ __launch_bounds__(256) void prep_kernel(
    const float* __restrict__ fc_w, _Float16* __restrict__ west)
{
    const int tid = threadIdx.x;
#pragma unroll
    for (int i = 0; i < 4; ++i) {
        int slot = i * 256 + tid;          // 0..1023
        int pair = slot >> 6, lane = slot & 63;
        int kt = pair >> 2, nt = pair & 3;
        int lr = lane & 15, g = lane >> 4;
        const float* wp = fc_w + (nt * 16 + lr) * C_ + kt * 32 + g * 8;
        float4 wa = *(const float4*)wp;
        float4 wb = *(const float4*)(wp + 4);
        f16x8 f;
        f[0] = (_Float16)wa.x; f[1] = (_Float16)wa.y;
        f[2] = (_Float16)wa.z; f[3] = (_Float16)wa.w;
        f[4] = (_Float16)wb.x; f[5] = (_Float16)wb.y;
        f[6] = (_Float16)wb.z; f[7] = (_Float16)wb.w;
        *(f16x8*)&west[slot * 8] = f;
    }
}

// ---------------------------------------------------------------------------
// Fused v6: single xC, 3 barriers/tile, 40.5 KB LDS; W frags loaded from
// frag-ordered global (L1-hot) each tile — NOT held in 64 regs (occupancy).
// Grid 768 = 16 n x 48 blocks, n-aligned tile ranges -> one private slab per
// block, plain stores (no atomics). reduce_kernel sums the 48 partials.
// ---------------------------------------------------------------------------
__global__ __launch_bounds__(256, 2) void fused_kernel(
    const float* __restrict__ x, const _Float16* __restrict__ west,
    const float* __restrict__ fc_b, float* __restrict__ vlad_part,
    float* __restrict__ a_part)
{
    __shared__ _Float16 xT[64 * 128];    // 16 KB [s][c]
    __shared__ _Float16 xC[128 * 64];    // 16 KB [c][s]
    __shared__ _Float16 sst[64 * 64];    //  8 KB [k][s]
    __shared__ float rns[2][64];         // 512 B, rotation-zeroed

    const int tid = threadIdx.x;
    const int lane = tid & 63, w = tid >> 6;
    const int lr = lane & 15, g = lane >> 4;
    const int fsw = (lr & 7) << 3;       // swizzle for rows of form m*16+lr

    // n-aligned ranges: per n, 16 blocks x 6 tiles + 32 blocks x 5 tiles = 256
    const int b = blockIdx.x;
    const int n = b / 48, j = b % 48;
    const int lo  = (j < 16) ? j * 6 : 96 + (j - 16) * 5;   // tile-in-n
    const int cnt = (j < 16) ? 6 : 5;

    if (tid < 128) (&rns[0][0])[tid] = 0.f;   // zero both rns buffers

    float bias[4];
#pragma unroll
    for (int nt = 0; nt < 4; ++nt) bias[nt] = fc_b[nt * 16 + lr];
    float a_acc[4] = {0.f, 0.f, 0.f, 0.f};
    f32x4 vacc[8];
#pragma unroll
    for (int nt = 0; nt < 8; ++nt) vacc[nt] = (f32x4){0.f, 0.f, 0.f, 0.f};

    const float* xb = x + (size_t)n * C_ * S_;
    const int s4 = tid & 15;
    int cqv[2];
#pragma unroll
    for (int i = 0; i < 2; ++i) cqv[i] = i * 16 + (tid >> 4);

    // prefetch first tile
    float4 pre[2][4];
#pragma unroll
    for (int i = 0; i < 2; ++i)
#pragma unroll
        for (int cc = 0; cc < 4; ++cc)
            pre[i][cc] = *(const float4*)(xb + (size_t)(cqv[i] * 4 + cc) * S_ +
                                          lo * 64 + s4 * 4);

#pragma unroll 1
    for (int it = 0; it < cnt; ++it) {
        __syncthreads();   // A: xT/xC/sst free (vlad(it-1) done); rns ok @it=0

        // ---- stage tile: xT (4x4 transpose) + xC + norm partials ----
        float part[4] = {0.f, 0.f, 0.f, 0.f};
#pragma unroll
        for (int i = 0; i < 2; ++i) {
            int cq = cqv[i];
#pragma unroll
            for (int jj = 0; jj < 4; ++jj) {
                float v0 = (&pre[i][0].x)[jj], v1 = (&pre[i][1].x)[jj],
                      v2 = (&pre[i][2].x)[jj], v3 = (&pre[i][3].x)[jj];
                part[jj] += v0 * v0 + v1 * v1 + v2 * v2 + v3 * v3;
                f16x4 p = {(_Float16)v0, (_Float16)v1, (_Float16)v2, (_Float16)v3};
                int s = s4 * 4 + jj;
                *(f16x4*)&xT[s * 128 + ((cq * 4) ^ SWZ_S(s))] = p;
            }
#pragma unroll
            for (int cc = 0; cc < 4; ++cc) {
                int c = cq * 4 + cc;
                f16x4 q = {(_Float16)pre[i][cc].x, (_Float16)pre[i][cc].y,
                           (_Float16)pre[i][cc].z, (_Float16)pre[i][cc].w};
                *(f16x4*)&xC[c * 64 + ((s4 * 4) ^ ((c & 7) << 3))] = q;
            }
        }
#pragma unroll
        for (int jj = 0; jj < 4; ++jj) {
            part[jj] += __shfl_xor(part[jj], 16);
            part[jj] += __shfl_xor(part[jj], 32);
        }
        if (g == 0) {
#pragma unroll
            for (int jj = 0; jj < 4; ++jj)
                atomicAdd(&rns[it & 1][lr * 4 + jj], part[jj]);
        }
        // prefetch next tile (stays in flight across barriers)
        if (it + 1 < cnt) {
            const float* xb2 = xb + (lo + it + 1) * 64;
#pragma unroll
            for (int i = 0; i < 2; ++i)
#pragma unroll
                for (int cc = 0; cc < 4; ++cc)
                    pre[i][cc] = *(const float4*)(xb2 + (size_t)(cqv[i] * 4 + cc) * S_ + s4 * 4);
        }
        __syncthreads();   // B: xT/xC/rns visible

        // keep W-frag loads inside the loop (prevent 64-reg LICM hoist)
        asm volatile("" ::: "memory");

        // ---- logits GEMM: D[s][k], wave w owns s-rows [16w,16w+16) ----
        f32x4 acc[4];
#pragma unroll
        for (int nt = 0; nt < 4; ++nt) acc[nt] = (f32x4){0.f, 0.f, 0.f, 0.f};
        __builtin_amdgcn_s_setprio(1);
#pragma unroll
        for (int kt = 0; kt < 4; ++kt) {
            const int co = kt * 32 + g * 8;
            const int sa = w * 16 + lr;
            f16x8 af = *(const f16x8*)&xT[sa * 128 + (co ^ SWZ_S(sa))];
#pragma unroll
            for (int nt = 0; nt < 4; ++nt) {
                f16x8 wf = *(const f16x8*)&west[(size_t)(((kt * 4 + nt) * 64 + lane)) * 8];
                acc[nt] = __builtin_amdgcn_mfma_f32_16x16x32_f16(af, wf, acc[nt], 0, 0, 0);
            }
        }
        __builtin_amdgcn_s_setprio(0);

        // ---- softmax over k (4 nt regs x 16 lr lanes), soft' -> sst ----
        {
            float rnl[4], ai[4];
#pragma unroll
            for (int r = 0; r < 4; ++r) {
                float ss = rns[it & 1][w * 16 + g * 4 + r];
                rnl[r] = 1.0f / fmaxf(sqrtf(ss), 1e-12f);
            }
#pragma unroll
            for (int nt = 0; nt < 4; ++nt)
#pragma unroll
                for (int r = 0; r < 4; ++r)
                    acc[nt][r] = __expf(acc[nt][r] * rnl[r] + bias[nt]);
#pragma unroll
            for (int r = 0; r < 4; ++r) {
                float sum = (acc[0][r] + acc[1][r]) + (acc[2][r] + acc[3][r]);
                sum += __shfl_xor(sum, 1);
                sum += __shfl_xor(sum, 2);
                sum += __shfl_xor(sum, 4);
                sum += __shfl_xor(sum, 8);
                float bi = 1.0f / sum;
                ai[r] = bi * rnl[r];
#pragma unroll
                for (int nt = 0; nt < 4; ++nt) a_acc[nt] += acc[nt][r] * bi;
            }
#pragma unroll
            for (int nt = 0; nt < 4; ++nt) {
                int k = nt * 16 + lr;
                int sloc = w * 16 + g * 4;
                f16x4 p = {(_Float16)(acc[nt][0] * ai[0]), (_Float16)(acc[nt][1] * ai[1]),
                           (_Float16)(acc[nt][2] * ai[2]), (_Float16)(acc[nt][3] * ai[3])};
                *(f16x4*)&sst[k * 64 + (sloc ^ ((k & 7) << 3))] = p;
            }
        }
        // rotation-zero the OTHER rns buffer
        if (tid < 64) rns[(it + 1) & 1][tid] = 0.f;
        __syncthreads();   // C: sst visible

        // ---- vlad GEMM: D[k][c], wave w owns k-tile w; accumulate vacc ----
        __builtin_amdgcn_s_setprio(1);
#pragma unroll
        for (int kt = 0; kt < 2; ++kt) {
            const int so = kt * 32 + g * 8;
            f16x8 pa = *(const f16x8*)&sst[(w * 16 + lr) * 64 + (so ^ fsw)];
#pragma unroll
            for (int nt = 0; nt < 8; ++nt) {
                f16x8 xv = *(const f16x8*)&xC[(nt * 16 + lr) * 64 + (so ^ fsw)];
                vacc[nt] = __builtin_amdgcn_mfma_f32_16x16x32_f16(pa, xv, vacc[nt], 0, 0, 0);
            }
        }
        __builtin_amdgcn_s_setprio(0);
    }

    // ---- flush: plain stores to this block's private slab ----
    float* vp = vlad_part + (size_t)b * (K_ * C_) + (w * 16) * C_;
#pragma unroll
    for (int nt = 0; nt < 8; ++nt)
#pragma unroll
        for (int r = 0; r < 4; ++r)
            vp[(g * 4 + r) * C_ + nt * 16 + lr] = vacc[nt][r];
#pragma unroll
    for (int nt = 0; nt < 4; ++nt) {
        a_acc[nt] += __shfl_xor(a_acc[nt], 16);
        a_acc[nt] += __shfl_xor(a_acc[nt], 32);
    }
    if (lane < 16) {
#pragma unroll
        for (int nt = 0; nt < 4; ++nt)
            a_part[b * 256 + w * 64 + nt * 16 + lr] = a_acc[nt];
    }
}

// ---------------------------------------------------------------------------
// Reduce: vlad_sum[n][e] = sum_{j<48} vlad_part[n*48+j][e]
// ---------------------------------------------------------------------------
__global__ __launch_bounds__(256) void reduce_kernel(
    const float* __restrict__ vlad_part, float* __restrict__ vlad_sum)
{
    const int n = blockIdx.x >> 5, chunk = blockIdx.x & 31;
    const int e = chunk * 256 + threadIdx.x;     // (k*128+c)
    const float* p = vlad_part + (size_t)(n * 48) * (K_ * C_) + e;
    float acc = 0.f;
#pragma unroll
    for (int j = 0; j < 48; ++j) acc += p[(size_t)j * (K_ * C_)];
    vlad_sum[n * (K_ * C_) + e] = acc;
}

// ---------------------------------------------------------------------------
// Finalize: a_sum reduce (48 chunks x 4 waves); vlad -= a_sum*centroids;
// intra-norm over C; global norm. Grid 16 x 1024; t: k=t>>4, q=t&15.
// ---------------------------------------------------------------------------
__global__ __launch_bounds__(1024) void finalize_kernel(
    const float* __restrict__ vlad_sum, const float* __restrict__ a_part,
    const float* __restrict__ centroids, float* __restrict__ out)
{
    __shared__ float red[16];
    const int n = blockIdx.x;
    const int t = threadIdx.x;
    const int k = t >> 4, q = t & 15;

    // a_sum[k]: 48 chunks x 4 waves; q handles chunks q*3..q*3+2
    float av = 0.f;
#pragma unroll
    for (int cc = 0; cc < 3; ++cc) {
        int ch = q * 3 + cc;
        const float* ap = a_part + (size_t)(n * 48 + ch) * 256 + k;
#pragma unroll
        for (int ww = 0; ww < 4; ++ww) av += ap[ww * 64];
    }
    av += __shfl_xor(av, 1);
    av += __shfl_xor(av, 2);
    av += __shfl_xor(av, 4);
    av += __shfl_xor(av, 8);

    const float* vp = vlad_sum + (size_t)n * (K_ * C_) + k * C_;
    const float* cp = centroids + k * C_;
    float v[8];
    float ssq = 0.f;
#pragma unroll
    for (int jj = 0; jj < 8; ++jj) {
        int c = q + 16 * jj;
        float val = vp[c] - av * cp[c];
        v[jj] = val;
        ssq += val * val;
    }
    ssq += __shfl_xor(ssq, 1);
    ssq += __shfl_xor(ssq, 2);
    ssq += __shfl_xor(ssq, 4);
    ssq += __shfl_xor(ssq, 8);
    const float inv1 = 1.0f / fmaxf(sqrtf(ssq), 1e-12f);

    float gp = (q == 0) ? ssq * inv1 * inv1 : 0.f;
#pragma unroll
    for (int off = 1; off < 64; off <<= 1) gp += __shfl_xor(gp, off);
    if ((t & 63) == 0) red[t >> 6] = gp;
    __syncthreads();
    float G = 0.f;
#pragma unroll
    for (int i = 0; i < 16; ++i) G += red[i];
    const float ginv = 1.0f / fmaxf(sqrtf(G), 1e-12f);

    float* op = out + (size_t)n * (K_ * C_) + k * C_;
#pragma unroll
    for (int jj = 0; jj < 8; ++jj) op[q + 16 * jj] = v[jj] * inv1 * ginv;
}

extern "C" void kernel_launch(void* const* d_in, const int* in_sizes, int n_in,
                              void* d_out, int out_size, void* d_ws, size_t ws_size,
                              hipStream_t stream) {
    const float* x     = (const float*)d_in[0];
    const float* fc_w  = (const float*)d_in[1];
    const float* fc_b  = (const float*)d_in[2];
    const float* cent  = (const float*)d_in[3];
    float* out = (float*)d_out;

    char* ws = (char*)d_ws;
    _Float16* west   = (_Float16*)ws;                         // 16 KB
    float* a_part    = (float*)(ws + 16384);                  // 768 KB
    float* vlad_part = (float*)(ws + 16384 + 786432);         // 24 MB
    float* vlad_sum  = (float*)(ws + 16384 + 786432 + 25165824);  // 512 KB

    prep_kernel<<<1, 256, 0, stream>>>(fc_w, west);
    fused_kernel<<<768, 256, 0, stream>>>(x, west, fc_b, vlad_part, a_part);
    reduce_kernel<<<512, 256, 0, stream>>>(vlad_part, vlad_sum);
    finalize_kernel<<<N_, 1024, 0, stream>>>(vlad_sum, a_part, cent, out);
}

// Round 10
// 53.855 us; speedup vs baseline: 1.3414x; 1.3414x over previous
//
#include <hip/hip_runtime.h>
#include <hip/hip_fp16.h>

#define N_ 16
#define C_ 128
#define S_ 16384
#define K_ 64

typedef __attribute__((ext_vector_type(4))) float f32x4;
typedef __attribute__((ext_vector_type(8))) _Float16 f16x8;
typedef __attribute__((ext_vector_type(4))) _Float16 f16x4;

// xT row-swizzle: varies with staging rows s=4*s4+j AND frag rows s=16m+lr.
#define SWZ_S(s) ((((s) ^ ((s) >> 3)) & 7) << 3)

// ---------------------------------------------------------------------------
// Fused v7 = r6 structure (2 barriers/tile, xC dbuf, wfrag in regs, slab
// flush) + software-pipelined softmax:
//   S1: stage xT/xC[b](i) + norms(i) + SOFTMAX(i-1)->sst + prefetch(i+1)
//   S2: logits(i) MFMA + vlad(i-1) MFMA          (pure LDS-read + MFMA)
// Logits accp carried in regs across the barrier. 56.5 KB LDS -> 2 blocks/CU.
// ---------------------------------------------------------------------------
__global__ __launch_bounds__(256, 2) void fused_kernel(
    const float* __restrict__ x, const float* __restrict__ fc_w,
    const float* __restrict__ fc_b, float* __restrict__ vlad_part,
    float* __restrict__ a_part)
{
    __shared__ _Float16 xT[64 * 128];     // 16 KB [s][c]
    __shared__ _Float16 xC[2][128 * 64];  // 32 KB [c][s] double-buffered
    __shared__ _Float16 sst[64 * 64];     //  8 KB [k][s]
    __shared__ float rns[2][64];          // 512 B, rotation-zeroed

    const int tid = threadIdx.x;
    const int n = blockIdx.x >> 5;
    const int chunk = blockIdx.x & 31;
    const int lane = tid & 63, w = tid >> 6;
    const int lr = lane & 15, g = lane >> 4;
    const int fsw = (lr & 7) << 3;        // swizzle for rows of form m*16+lr

    // ---- W B-fragments in registers (tile-invariant) ----
    f16x8 wfrag[4][4];
#pragma unroll
    for (int nt = 0; nt < 4; ++nt)
#pragma unroll
        for (int kt = 0; kt < 4; ++kt) {
            const float* wp = fc_w + (nt * 16 + lr) * C_ + kt * 32 + g * 8;
            float4 wa = *(const float4*)wp;
            float4 wb = *(const float4*)(wp + 4);
            f16x8 f;
            f[0] = (_Float16)wa.x; f[1] = (_Float16)wa.y;
            f[2] = (_Float16)wa.z; f[3] = (_Float16)wa.w;
            f[4] = (_Float16)wb.x; f[5] = (_Float16)wb.y;
            f[6] = (_Float16)wb.z; f[7] = (_Float16)wb.w;
            wfrag[nt][kt] = f;
        }
    if (tid < 128) (&rns[0][0])[tid] = 0.f;   // zero both rns buffers

    float bias[4];
#pragma unroll
    for (int nt = 0; nt < 4; ++nt) bias[nt] = fc_b[nt * 16 + lr];
    float a_acc[4] = {0.f, 0.f, 0.f, 0.f};
    f32x4 vacc[8];
#pragma unroll
    for (int nt = 0; nt < 8; ++nt) vacc[nt] = (f32x4){0.f, 0.f, 0.f, 0.f};
    f32x4 accp[4];   // logits(i) carried S2(i) -> S1(i+1)

    const float* xb = x + (size_t)n * C_ * S_;
    const int s4 = tid & 15;
    int cqv[2];
#pragma unroll
    for (int i = 0; i < 2; ++i) cqv[i] = i * 16 + (tid >> 4);

    // prefetch tile 0
    float4 pre[2][4];
#pragma unroll
    for (int i = 0; i < 2; ++i)
#pragma unroll
        for (int cc = 0; cc < 4; ++cc)
            pre[i][cc] = *(const float4*)(xb + (size_t)(cqv[i] * 4 + cc) * S_ +
                                          chunk * 512 + s4 * 4);

    // softmax(prev) on accp -> sst, a_acc; reads+rezeroes rns[pit] (wave-private)
    auto softmax_emit = [&](int pit) {
        float rnl[4], ai[4];
#pragma unroll
        for (int r = 0; r < 4; ++r)
            rnl[r] = 1.0f / fmaxf(sqrtf(rns[pit][w * 16 + g * 4 + r]), 1e-12f);
        if (lane < 16) rns[pit][w * 16 + lane] = 0.f;  // same-wave DS order: safe
#pragma unroll
        for (int nt = 0; nt < 4; ++nt)
#pragma unroll
            for (int r = 0; r < 4; ++r)
                accp[nt][r] = __expf(accp[nt][r] * rnl[r] + bias[nt]);
#pragma unroll
        for (int r = 0; r < 4; ++r) {
            float sum = (accp[0][r] + accp[1][r]) + (accp[2][r] + accp[3][r]);
            sum += __shfl_xor(sum, 1);
            sum += __shfl_xor(sum, 2);
            sum += __shfl_xor(sum, 4);
            sum += __shfl_xor(sum, 8);
            float bi = 1.0f / sum;
            ai[r] = bi * rnl[r];
#pragma unroll
            for (int nt = 0; nt < 4; ++nt) a_acc[nt] += accp[nt][r] * bi;
        }
#pragma unroll
        for (int nt = 0; nt < 4; ++nt) {
            int k = nt * 16 + lr;
            int sloc = w * 16 + g * 4;
            f16x4 p = {(_Float16)(accp[nt][0] * ai[0]), (_Float16)(accp[nt][1] * ai[1]),
                       (_Float16)(accp[nt][2] * ai[2]), (_Float16)(accp[nt][3] * ai[3])};
            *(f16x4*)&sst[k * 64 + (sloc ^ ((k & 7) << 3))] = p;
        }
    };

#pragma unroll 1
    for (int it = 0; it < 8; ++it) {
        const int b = it & 1;
        __syncthreads();   // top: xT/sst consumed (S2(it-1)); xC[b] consumed

        // ---- S1: stage tile it ----
        float part[4] = {0.f, 0.f, 0.f, 0.f};
#pragma unroll
        for (int i = 0; i < 2; ++i) {
            int cq = cqv[i];
#pragma unroll
            for (int jj = 0; jj < 4; ++jj) {
                float v0 = (&pre[i][0].x)[jj], v1 = (&pre[i][1].x)[jj],
                      v2 = (&pre[i][2].x)[jj], v3 = (&pre[i][3].x)[jj];
                part[jj] += v0 * v0 + v1 * v1 + v2 * v2 + v3 * v3;
                f16x4 p = {(_Float16)v0, (_Float16)v1, (_Float16)v2, (_Float16)v3};
                int s = s4 * 4 + jj;
                *(f16x4*)&xT[s * 128 + ((cq * 4) ^ SWZ_S(s))] = p;
            }
#pragma unroll
            for (int cc = 0; cc < 4; ++cc) {
                int c = cq * 4 + cc;
                f16x4 q = {(_Float16)pre[i][cc].x, (_Float16)pre[i][cc].y,
                           (_Float16)pre[i][cc].z, (_Float16)pre[i][cc].w};
                *(f16x4*)&xC[b][c * 64 + ((s4 * 4) ^ ((c & 7) << 3))] = q;
            }
        }
#pragma unroll
        for (int jj = 0; jj < 4; ++jj) {
            part[jj] += __shfl_xor(part[jj], 16);
            part[jj] += __shfl_xor(part[jj], 32);
        }
        if (g == 0) {
#pragma unroll
            for (int jj = 0; jj < 4; ++jj)
                atomicAdd(&rns[it & 1][lr * 4 + jj], part[jj]);
        }
        // softmax(it-1) -> sst (overlaps staging; different pipes)
        if (it > 0) softmax_emit((it - 1) & 1);
        // prefetch tile it+1
        if (it < 7) {
            const float* xb2 = xb + chunk * 512 + (it + 1) * 64;
#pragma unroll
            for (int i = 0; i < 2; ++i)
#pragma unroll
                for (int cc = 0; cc < 4; ++cc)
                    pre[i][cc] = *(const float4*)(xb2 + (size_t)(cqv[i] * 4 + cc) * S_ + s4 * 4);
        }
        __syncthreads();   // xT/xC[b]/sst/rns visible

        // ---- S2: pure MFMA + LDS reads ----
#pragma unroll
        for (int nt = 0; nt < 4; ++nt) accp[nt] = (f32x4){0.f, 0.f, 0.f, 0.f};
        __builtin_amdgcn_s_setprio(1);
#pragma unroll
        for (int kt = 0; kt < 4; ++kt) {
            const int co = kt * 32 + g * 8;
            const int sa = w * 16 + lr;
            f16x8 af = *(const f16x8*)&xT[sa * 128 + (co ^ SWZ_S(sa))];
#pragma unroll
            for (int nt = 0; nt < 4; ++nt)
                accp[nt] = __builtin_amdgcn_mfma_f32_16x16x32_f16(af, wfrag[nt][kt], accp[nt], 0, 0, 0);
        }
        if (it > 0) {
            const _Float16* xcp = xC[b ^ 1];
#pragma unroll
            for (int kt = 0; kt < 2; ++kt) {
                const int so = kt * 32 + g * 8;
                f16x8 pa = *(const f16x8*)&sst[(w * 16 + lr) * 64 + (so ^ fsw)];
#pragma unroll
                for (int nt = 0; nt < 8; ++nt) {
                    f16x8 xv = *(const f16x8*)&xcp[(nt * 16 + lr) * 64 + (so ^ fsw)];
                    vacc[nt] = __builtin_amdgcn_mfma_f32_16x16x32_f16(pa, xv, vacc[nt], 0, 0, 0);
                }
            }
        }
        __builtin_amdgcn_s_setprio(0);
    }

    // ---- epilogue: softmax(7) -> sst, then vlad(7) ----
    __syncthreads();
    softmax_emit(1);   // 7 & 1
    __syncthreads();
    {
        const _Float16* xcp = xC[1];   // tile 7 parity
#pragma unroll
        for (int kt = 0; kt < 2; ++kt) {
            const int so = kt * 32 + g * 8;
            f16x8 pa = *(const f16x8*)&sst[(w * 16 + lr) * 64 + (so ^ fsw)];
#pragma unroll
            for (int nt = 0; nt < 8; ++nt) {
                f16x8 xv = *(const f16x8*)&xcp[(nt * 16 + lr) * 64 + (so ^ fsw)];
                vacc[nt] = __builtin_amdgcn_mfma_f32_16x16x32_f16(pa, xv, vacc[nt], 0, 0, 0);
            }
        }
    }

    // ---- flush: plain stores to this block's private slab ----
    float* vp = vlad_part + (size_t)blockIdx.x * (K_ * C_) + (w * 16) * C_;
#pragma unroll
    for (int nt = 0; nt < 8; ++nt)
#pragma unroll
        for (int r = 0; r < 4; ++r)
            vp[(g * 4 + r) * C_ + nt * 16 + lr] = vacc[nt][r];
#pragma unroll
    for (int nt = 0; nt < 4; ++nt) {
        a_acc[nt] += __shfl_xor(a_acc[nt], 16);
        a_acc[nt] += __shfl_xor(a_acc[nt], 32);
    }
    if (lane < 16) {
#pragma unroll
        for (int nt = 0; nt < 4; ++nt)
            a_part[blockIdx.x * 256 + w * 64 + nt * 16 + lr] = a_acc[nt];
    }
}

// ---------------------------------------------------------------------------
// Reduce: vlad_sum[n][e] = sum_{ch<32} vlad_part[n*32+ch][e]
// ---------------------------------------------------------------------------
__global__ __launch_bounds__(256) void reduce_kernel(
    const float* __restrict__ vlad_part, float* __restrict__ vlad_sum)
{
    const int n = blockIdx.x >> 5, g8 = blockIdx.x & 31;
    const int e = g8 * 256 + threadIdx.x;        // (k*128+c)
    const float* p = vlad_part + (size_t)(n * 32) * (K_ * C_) + e;
    float acc = 0.f;
#pragma unroll
    for (int ch = 0; ch < 32; ++ch) acc += p[(size_t)ch * (K_ * C_)];
    vlad_sum[n * (K_ * C_) + e] = acc;
}

// ---------------------------------------------------------------------------
// Finalize: a_sum reduce (32 chunks x 4 waves); vlad -= a_sum*centroids;
// intra-norm over C; global norm. Grid 16 x 1024; t: k=t>>4, q=t&15.
// ---------------------------------------------------------------------------
__global__ __launch_bounds__(1024) void finalize_kernel(
    const float* __restrict__ vlad_sum, const float* __restrict__ a_part,
    const float* __restrict__ centroids, float* __restrict__ out)
{
    __shared__ float red[16];
    const int n = blockIdx.x;
    const int t = threadIdx.x;
    const int k = t >> 4, q = t & 15;

    float av = 0.f;
#pragma unroll
    for (int cc = 0; cc < 2; ++cc) {
        int ch = q * 2 + cc;
        const float* ap = a_part + (size_t)(n * 32 + ch) * 256 + k;
#pragma unroll
        for (int ww = 0; ww < 4; ++ww) av += ap[ww * 64];
    }
    av += __shfl_xor(av, 1);
    av += __shfl_xor(av, 2);
    av += __shfl_xor(av, 4);
    av += __shfl_xor(av, 8);

    const float* vp = vlad_sum + (size_t)n * (K_ * C_) + k * C_;
    const float* cp = centroids + k * C_;
    float v[8];
    float ssq = 0.f;
#pragma unroll
    for (int jj = 0; jj < 8; ++jj) {
        int c = q + 16 * jj;
        float val = vp[c] - av * cp[c];
        v[jj] = val;
        ssq += val * val;
    }
    ssq += __shfl_xor(ssq, 1);
    ssq += __shfl_xor(ssq, 2);
    ssq += __shfl_xor(ssq, 4);
    ssq += __shfl_xor(ssq, 8);
    const float inv1 = 1.0f / fmaxf(sqrtf(ssq), 1e-12f);

    float gp = (q == 0) ? ssq * inv1 * inv1 : 0.f;
#pragma unroll
    for (int off = 1; off < 64; off <<= 1) gp += __shfl_xor(gp, off);
    if ((t & 63) == 0) red[t >> 6] = gp;
    __syncthreads();
    float G = 0.f;
#pragma unroll
    for (int i = 0; i < 16; ++i) G += red[i];
    const float ginv = 1.0f / fmaxf(sqrtf(G), 1e-12f);

    float* op = out + (size_t)n * (K_ * C_) + k * C_;
#pragma unroll
    for (int jj = 0; jj < 8; ++jj) op[q + 16 * jj] = v[jj] * inv1 * ginv;
}

extern "C" void kernel_launch(void* const* d_in, const int* in_sizes, int n_in,
                              void* d_out, int out_size, void* d_ws, size_t ws_size,
                              hipStream_t stream) {
    const float* x     = (const float*)d_in[0];
    const float* fc_w  = (const float*)d_in[1];
    const float* fc_b  = (const float*)d_in[2];
    const float* cent  = (const float*)d_in[3];
    float* out = (float*)d_out;

    char* ws = (char*)d_ws;
    float* vlad_part = (float*)ws;                                   // 16 MB
    float* a_part    = (float*)(ws + (size_t)512 * K_ * C_ * 4);     // 512 KB
    float* vlad_sum  = (float*)(ws + (size_t)512 * K_ * C_ * 4 + 512 * 1024);

    fused_kernel<<<N_ * 32, 256, 0, stream>>>(x, fc_w, fc_b, vlad_part, a_part);
    reduce_kernel<<<N_ * 32, 256, 0, stream>>>(vlad_part, vlad_sum);
    finalize_kernel<<<N_, 1024, 0, stream>>>(vlad_sum, a_part, cent, out);
}